// Round 5
// baseline (478.065 us; speedup 1.0000x reference)
//
#include <hip/hip_runtime.h>
#include <hip/hip_bf16.h>

typedef unsigned short u16;
typedef unsigned int   u32;
typedef __attribute__((ext_vector_type(8))) short short8;
typedef __attribute__((ext_vector_type(4))) float f32x4;

#define BB  4
#define LL  32777
#define MM  4097
#define MMP 4112
#define MM2 512

__device__ __forceinline__ float b2f(u16 u) { return __uint_as_float(((u32)u) << 16); }
__device__ __forceinline__ u16 f2bf(float f) {           // cold path only (setup swizzles)
    u32 u = __float_as_uint(f);
    return (u16)((u + 0x7fffu + ((u >> 16) & 1u)) >> 16);   // RNE
}
// HW v_cvt_pk_bf16_f32 (RNE) — a in low 16, b in high 16
__device__ __forceinline__ u32 pk(float a, float b) {
    union { __hip_bfloat162 h; u32 u; } cv;
    cv.h = __float22bfloat162_rn(make_float2(a, b));
    return cv.u;
}
__device__ __forceinline__ float bflo(u32 u) { return __uint_as_float(u << 16); }
__device__ __forceinline__ float bfhi(u32 u) { return __uint_as_float(u & 0xffff0000u); }

// ---------- setup: weight swizzles only ----------
__global__ __launch_bounds__(256) void setup_k(
    const float* __restrict__ wagg1, const float* __restrict__ wagg2,
    const float* __restrict__ wsrc1, const float* __restrict__ wsrc2,
    const float* __restrict__ watt,
    u16* __restrict__ wA1, u16* __restrict__ wA2,
    u16* __restrict__ wS1, u16* __restrict__ wS2, u16* __restrict__ wattB) {
    int idx = blockIdx.x * 256 + threadIdx.x;      // 0..167935
    if (idx < 131072) {
        int which = idx >> 16;
        int e = idx & 65535;
        int j = e & 7, lane = (e >> 3) & 63, mt = (e >> 9) & 3, kc = (e >> 11) & 7, g = (e >> 14) & 3;
        int ol = mt * 16 + (lane & 15);
        int k = kc * 32 + (lane >> 4) * 8 + j;
        int t = k >> 6, ci = k & 63;
        const float* src = which ? wagg2 : wagg1;
        u16* dst = which ? wA2 : wA1;
        dst[e] = f2bf(src[(g * 64 + ol) * 256 + ci * 4 + t]);
    } else if (idx < 163840) {
        int e2 = idx - 131072;
        int which = e2 >> 14;
        int e = e2 & 16383;
        int j = e & 7, lane = (e >> 3) & 63, mt = (e >> 9) & 3, kc = (e >> 11) & 1, g = (e >> 12) & 3;
        int ol = mt * 16 + (lane & 15);
        int k = kc * 32 + (lane >> 4) * 8 + j;
        const float* src = which ? wsrc2 : wsrc1;
        u16* dst = which ? wS2 : wS1;
        dst[e] = f2bf(src[(g * 64 + ol) * 64 + k]);
    } else {
        int e = idx - 163840;                      // 0..4095
        int j = e & 7, lane = (e >> 3) & 63, kc = e >> 9;
        int h = lane & 15, quad = lane >> 4;
        int k = kc * 32 + quad * 8 + j;
        wattB[e] = (h < 4) ? f2bf(watt[k * 4 + h]) : (u16)0;
    }
}

// row/dst/key helper for one staging slot
__device__ __forceinline__ void stage_addr(int p0i, int r, int& grow, int& key, bool& val, int& lr) {
    if (r < 64) {
        int pos = r >> 3, nn = r & 7;
        int gp = p0i + pos; int gpc = gp < MM ? gp : MM - 1;
        grow = 1 + 8 * gpc + nn;
        key = (pos ^ nn) & 7;
        val = true; lr = r;
    } else {
        int q = r - 64; int qq = q < 8 ? q : 7;
        int gp = p0i + qq; int gpc = gp < MM ? gp : MM - 1;
        grow = gpc;
        key = qq & 7;
        val = (q < 8); lr = qq;
    }
}

// asm stage-issue (prologue only: wait follows immediately, zero hazard window)
__device__ __forceinline__ void stage_issue_asm(const float* xb, int p0i, int rslot, int cseg,
                                                float4* v0, float4* v1, float4* v2, float4* v3) {
    #pragma unroll
    for (int pass = 0; pass < 5; ++pass) {
        int grow, key, lr; bool val;
        stage_addr(p0i, pass * 16 + rslot, grow, key, val, lr);
        const float* sp = xb + (size_t)grow * 256 + cseg * 16;
        asm volatile("global_load_dwordx4 %0, %1, off"           : "=v"(v0[pass]) : "v"(sp));
        asm volatile("global_load_dwordx4 %0, %1, off offset:16" : "=v"(v1[pass]) : "v"(sp));
        asm volatile("global_load_dwordx4 %0, %1, off offset:32" : "=v"(v2[pass]) : "v"(sp));
        asm volatile("global_load_dwordx4 %0, %1, off offset:48" : "=v"(v3[pass]) : "v"(sp));
    }
}

// compiler-visible stage-issue (in-loop prefetch: spill-safe by construction)
__device__ __forceinline__ void stage_issue_cpp(const float* xb, int p0i, int rslot, int cseg,
                                                float4* v0, float4* v1, float4* v2, float4* v3) {
    #pragma unroll
    for (int pass = 0; pass < 5; ++pass) {
        int grow, key, lr; bool val;
        stage_addr(p0i, pass * 16 + rslot, grow, key, val, lr);
        const float4* sp = (const float4*)(xb + (size_t)grow * 256 + cseg * 16);
        v0[pass] = sp[0]; v1[pass] = sp[1]; v2[pass] = sp[2]; v3[pass] = sp[3];
    }
}

// stage-write: convert staged registers to bf16 and store swizzled into LDS
__device__ __forceinline__ void stage_write(u16* sh_node, u16* sh_srcq, int rslot, int cseg,
                                            const float4* v0, const float4* v1,
                                            const float4* v2, const float4* v3) {
    #pragma unroll
    for (int pass = 0; pass < 5; ++pass) {
        int r = pass * 16 + rslot;
        u16* dst; int key; bool val = true;
        if (r < 64) {
            int pos = r >> 3, nn = r & 7;
            dst = sh_node + r * 256;
            key = (pos ^ nn) & 7;
        } else {
            int q = r - 64;
            val = (q < 8);
            int qq = q < 8 ? q : 7;
            dst = sh_srcq + qq * 256;
            key = qq & 7;
        }
        if (val) {
            uint4 o0, o1;
            o0.x = pk(v0[pass].x, v0[pass].y); o0.y = pk(v0[pass].z, v0[pass].w);
            o0.z = pk(v1[pass].x, v1[pass].y); o0.w = pk(v1[pass].z, v1[pass].w);
            o1.x = pk(v2[pass].x, v2[pass].y); o1.y = pk(v2[pass].z, v2[pass].w);
            o1.z = pk(v3[pass].x, v3[pass].y); o1.w = pk(v3[pass].z, v3[pass].w);
            int cb0 = cseg * 2;
            *(uint4*)(dst + ((cb0 ^ key) * 8))       = o0;
            *(uint4*)(dst + (((cb0 + 1) ^ key) * 8)) = o1;
        }
    }
}

// ---------- fused layer1 (x>=64, 2-tile pipelined) + gt double-GEMM (x<64) ----------
__global__ __launch_bounds__(256, 3) void l1fused_k(
    const float* __restrict__ x, const float* __restrict__ batt,
    const u16* __restrict__ wA1, const u16* __restrict__ wS1,
    const u16* __restrict__ wattB,
    const float* __restrict__ bagg1, const float* __restrict__ bsrc1,
    float* __restrict__ attnf, u16* __restrict__ out1, float* __restrict__ n1m0,
    const float* __restrict__ gt, const float* __restrict__ W1, const float* __restrict__ b1,
    const float* __restrict__ W2, const float* __restrict__ b2,
    float* __restrict__ gt2, float* __restrict__ gt1m0) {
    __shared__ u16   sh_node[64 * 256];    // [r=pos*8+n][cb^((pos^n)&7)] bf16, 32 KB
    __shared__ u16   sh_srcq[8 * 256];     // [q][cb^(q&7)] bf16, 4 KB; aliased as out tile
    __shared__ float shR[320];             // rdN[0..255], rdS[256..319]

    int tid = threadIdx.x;
    int b = blockIdx.y;

    if (blockIdx.x < 64) {
        // ---- fused gt GEMM: gt1 in LDS, gt2 to global ----
        float (*sh)[8] = (float(*)[8])sh_node;     // 8 KB alias
        int gi = blockIdx.x * 4 + b;               // 0..255
        int row0 = gi * 8;
        {
            int r = tid >> 5, j = tid & 31;
            const float4* a4 = (const float4*)(gt + (size_t)(row0 + r) * 256 + j * 8);
            float4 v0 = a4[0], v1 = a4[1];
            sh[j * 8 + 0][r] = v0.x; sh[j * 8 + 1][r] = v0.y;
            sh[j * 8 + 2][r] = v0.z; sh[j * 8 + 3][r] = v0.w;
            sh[j * 8 + 4][r] = v1.x; sh[j * 8 + 5][r] = v1.y;
            sh[j * 8 + 6][r] = v1.z; sh[j * 8 + 7][r] = v1.w;
        }
        __syncthreads();
        int o = tid;
        float acc[8];
        {
            float bo = b1[o];
            #pragma unroll
            for (int i = 0; i < 8; ++i) acc[i] = bo;
        }
        #pragma unroll 16
        for (int k = 0; k < 256; ++k) {
            float wv = W1[k * 256 + o];
            const float4* ap = (const float4*)&sh[k][0];
            float4 a0 = ap[0], a1 = ap[1];
            acc[0] = fmaf(a0.x, wv, acc[0]); acc[1] = fmaf(a0.y, wv, acc[1]);
            acc[2] = fmaf(a0.z, wv, acc[2]); acc[3] = fmaf(a0.w, wv, acc[3]);
            acc[4] = fmaf(a1.x, wv, acc[4]); acc[5] = fmaf(a1.y, wv, acc[5]);
            acc[6] = fmaf(a1.z, wv, acc[6]); acc[7] = fmaf(a1.w, wv, acc[7]);
        }
        #pragma unroll
        for (int i = 0; i < 8; ++i) acc[i] = fmaxf(acc[i], 0.f);
        if ((row0 & 511) == 0) gt1m0[(row0 >> 9) * 256 + o] = acc[0];
        __syncthreads();
        #pragma unroll
        for (int i = 0; i < 8; ++i) sh[o][i] = acc[i];
        __syncthreads();
        {
            float bo = b2[o];
            #pragma unroll
            for (int i = 0; i < 8; ++i) acc[i] = bo;
        }
        #pragma unroll 16
        for (int k = 0; k < 256; ++k) {
            float wv = W2[k * 256 + o];
            const float4* ap = (const float4*)&sh[k][0];
            float4 a0 = ap[0], a1 = ap[1];
            acc[0] = fmaf(a0.x, wv, acc[0]); acc[1] = fmaf(a0.y, wv, acc[1]);
            acc[2] = fmaf(a0.z, wv, acc[2]); acc[3] = fmaf(a0.w, wv, acc[3]);
            acc[4] = fmaf(a1.x, wv, acc[4]); acc[5] = fmaf(a1.y, wv, acc[5]);
            acc[6] = fmaf(a1.z, wv, acc[6]); acc[7] = fmaf(a1.w, wv, acc[7]);
        }
        #pragma unroll
        for (int i = 0; i < 8; ++i) gt2[(size_t)(row0 + i) * 256 + o] = fmaxf(acc[i], 0.f);
        return;
    }

    int bxb = blockIdx.x - 64;     // 0..256; tiles bxb and bxb+257
    int nt = (bxb < 256) ? 2 : 1;
    int lane = tid & 63, w = tid >> 6;
    int quad = lane >> 4;
    int rslot = tid >> 4, cseg = tid & 15;
    const float* xb = x + (size_t)b * LL * 256;
    float battw = batt[w];

    float4 v0[5], v1[5], v2[5], v3[5];    // staged tile payload

    // prologue: stage tile 0 (asm issue -> immediate wait: zero hazard window)
    stage_issue_asm(xb, bxb * 8, rslot, cseg, v0, v1, v2, v3);
    asm volatile("s_waitcnt vmcnt(0)" ::: "memory");
    __builtin_amdgcn_sched_barrier(0);
    stage_write(sh_node, sh_srcq, rslot, cseg, v0, v1, v2, v3);
    __syncthreads();

    int g = w;
    int col = lane & 15;
    int pos = col & 7;

    for (int ti = 0; ti < nt; ++ti) {
        int tile = bxb + ti * 257;
        int p0 = tile * 8;
        bool pre = (ti + 1 < nt);

        // phase 1: rowdots via MFMA. wave w: node m-tile w; wave 3 also src tile.
        short8 wB[8];
        #pragma unroll
        for (int kc = 0; kc < 8; ++kc) wB[kc] = *(const short8*)(wattB + kc * 512 + lane * 8);
        {
            int m = lane & 15;
            int h = lane & 15;
            {
                int r = w * 16 + m;
                int key = ((r >> 3) ^ (r & 7)) & 7;
                const u16* rowp = sh_node + r * 256;
                f32x4 acc = (f32x4){0.f, 0.f, 0.f, 0.f};
                #pragma unroll
                for (int kc = 0; kc < 8; ++kc) {
                    int cb = kc * 4 + quad;
                    short8 aF = *(const short8*)(rowp + ((cb ^ key) * 8));
                    acc = __builtin_amdgcn_mfma_f32_16x16x32_bf16(aF, wB[kc], acc, 0, 0, 0);
                }
                if (h < 4) {
                    #pragma unroll
                    for (int r2 = 0; r2 < 4; ++r2)
                        shR[(w * 16 + quad * 4 + r2) * 4 + h] = acc[r2];
                }
            }
            if (w == 3) {
                int ms = m < 8 ? m : 7;
                int key = ms & 7;
                const u16* rowp = sh_srcq + ms * 256;
                f32x4 acc = (f32x4){0.f, 0.f, 0.f, 0.f};
                #pragma unroll
                for (int kc = 0; kc < 8; ++kc) {
                    int cb = kc * 4 + quad;
                    short8 aF = *(const short8*)(rowp + ((cb ^ key) * 8));
                    acc = __builtin_amdgcn_mfma_f32_16x16x32_bf16(aF, wB[kc], acc, 0, 0, 0);
                }
                if (h < 4) {
                    #pragma unroll
                    for (int r2 = 0; r2 < 4; ++r2) {
                        int rr = quad * 4 + r2;
                        if (rr < 8) shR[256 + rr * 4 + h] = acc[r2];
                    }
                }
            }
        }
        __syncthreads();

        // softmax per-lane (q=pos, h=g) straight into registers
        float aT[8];
        {
            float base = shR[256 + pos * 4 + g] + battw;
            float l[8], mx = -3.0e38f;
            #pragma unroll
            for (int n = 0; n < 8; ++n) { l[n] = shR[(pos * 8 + n) * 4 + g] + base; mx = fmaxf(mx, l[n]); }
            float s = 0.f;
            #pragma unroll
            for (int n = 0; n < 8; ++n) { l[n] = __expf(l[n] - mx); s += l[n]; }
            float inv = 1.f / s;
            #pragma unroll
            for (int n = 0; n < 8; ++n) aT[n] = l[n] * inv;
            int gp = p0 + pos;
            if (quad == 0 && col < 8 && gp < MM2) {
                #pragma unroll
                for (int n = 0; n < 8; ++n)
                    attnf[(((size_t)b * MM2 + gp) * 8 + n) * 4 + g] = aT[n];
            }
        }

        // phase 3a: node conv MFMA (last reads of sh_node)
        f32x4 accn[4];
        #pragma unroll
        for (int mt = 0; mt < 4; ++mt) accn[mt] = (f32x4){0, 0, 0, 0};
        const u16* wAb = wA1 + (size_t)(g * 8) * 4 * 512 + lane * 8;
        #pragma unroll
        for (int kc = 0; kc < 8; ++kc) {
            int k0 = kc * 32 + quad * 8;
            int t = k0 >> 6, ci0 = k0 & 63;
            int cb = (g * 64 + ci0) >> 3;
            int r0 = pos * 8 + 2 * t;
            int key0 = (pos ^ (2 * t)) & 7, key1 = (pos ^ (2 * t + 1)) & 7;
            short8 n0 = *(const short8*)(sh_node + r0 * 256 + ((cb ^ key0) * 8));
            short8 n1 = *(const short8*)(sh_node + (r0 + 1) * 256 + ((cb ^ key1) * 8));
            float a0 = aT[2 * t], a1 = aT[2 * t + 1];
            union { uint4 u; short8 s; } cv;
            #pragma unroll
            for (int e = 0; e < 4; ++e) {
                float lo = fmaf(a0, b2f((u16)n0[2 * e]),     a1 * b2f((u16)n1[2 * e]));
                float hi = fmaf(a0, b2f((u16)n0[2 * e + 1]), a1 * b2f((u16)n1[2 * e + 1]));
                ((u32*)&cv.u)[e] = pk(lo, hi);
            }
            short8 bB = cv.s;
            #pragma unroll
            for (int mt = 0; mt < 4; ++mt) {
                short8 aA = *(const short8*)(wAb + (kc * 4 + mt) * 512);
                accn[mt] = __builtin_amdgcn_mfma_f32_16x16x32_bf16(aA, bB, accn[mt], 0, 0, 0);
            }
        }

        // prefetch next tile (compiler-visible loads — spill-safe). sched_barrier
        // pins the issue here so the loads fly under accs + epilogue + out1 store.
        if (pre) {
            stage_issue_cpp(xb, (bxb + (ti + 1) * 257) * 8, rslot, cseg, v0, v1, v2, v3);
            __builtin_amdgcn_sched_barrier(0);
        }

        // phase 3b: src conv MFMA (last reads of sh_srcq)
        f32x4 accs[4];
        #pragma unroll
        for (int mt = 0; mt < 4; ++mt) accs[mt] = (f32x4){0, 0, 0, 0};
        #pragma unroll
        for (int kc = 0; kc < 2; ++kc) {
            int cb = (g * 64 + kc * 32 + quad * 8) >> 3;
            short8 bS = *(const short8*)(sh_srcq + pos * 256 + ((cb ^ pos) * 8));
            #pragma unroll
            for (int mt = 0; mt < 4; ++mt) {
                short8 aS = *(const short8*)(wS1 + (((g * 2 + kc) * 4 + mt) * 512 + lane * 8));
                accs[mt] = __builtin_amdgcn_mfma_f32_16x16x32_bf16(aS, bS, accs[mt], 0, 0, 0);
            }
        }
        __syncthreads();   // src reads done; reuse sh_srcq as out tile [pos][o]

        u16* outt = sh_srcq;
        #pragma unroll
        for (int mt = 0; mt < 4; ++mt) {
            int ob = g * 64 + mt * 16 + quad * 4;
            float v[4], n1v[4];
            #pragma unroll
            for (int r = 0; r < 4; ++r) {
                int o = ob + r;
                float n1 = fmaxf(accn[mt][r] + bagg1[o], 0.f);
                float s1 = fmaxf(accs[mt][r] + bsrc1[o], 0.f);
                n1v[r] = n1;
                v[r] = n1 + s1;
            }
            if (col < 8) {
                u32* wp = (u32*)&outt[col * 256 + ob];
                wp[0] = pk(v[0], v[1]);
                wp[1] = pk(v[2], v[3]);
            }
            if (tile == 0 && col == 0) {
                #pragma unroll
                for (int r = 0; r < 4; ++r) n1m0[b * 256 + ob + r] = n1v[r];
            }
        }
        __syncthreads();
        {
            int posw = tid >> 5, cc = (tid & 31) * 8;
            if (p0 + posw < MM)
                *(uint4*)&out1[((size_t)b * MMP + p0 + posw) * 256 + cc] = *(const uint4*)&outt[posw * 256 + cc];
        }
        if (pre) {
            __syncthreads();   // all waves done reading outt/sh_node of tile t
            stage_write(sh_node, sh_srcq, rslot, cseg, v0, v1, v2, v3);
            __syncthreads();   // tile t+1 staged
        }
    }
}

// ---------- layer2 conv + score2 (blocks x<128, 4 pos each) + score1 (x==128) ----------
__global__ __launch_bounds__(256) void l2conv_k(
    const u16* __restrict__ out1, const float* __restrict__ attnf,
    const float* __restrict__ gt2,
    const u16* __restrict__ wA2, const u16* __restrict__ wS2,
    const float* __restrict__ bagg2, const float* __restrict__ bsrc2,
    const float* __restrict__ gt1m0, const float* __restrict__ n1m0,
    float* __restrict__ outp, float* __restrict__ score2p, float* __restrict__ score1p) {
    __shared__ char shraw[16 * 268 * 4 * 2];
    __shared__ float shred[128];

    int tid = threadIdx.x;
    int b = blockIdx.y;

    if (blockIdx.x == 128) {            // fused score1
        float d = gt1m0[b * 256 + tid] - n1m0[b * 256 + tid];
        float v = d * d;
        #pragma unroll
        for (int off = 32; off > 0; off >>= 1) v += __shfl_down(v, off, 64);
        if ((tid & 63) == 0) shred[tid >> 6] = v;
        __syncthreads();
        if (tid == 0) score1p[b] = 1.f - __expf(-0.5f * (shred[0] + shred[1] + shred[2] + shred[3]));
        return;
    }

    int p0 = blockIdx.x * 4;           // 4 positions per block
    u16* aggl = (u16*)shraw;

    {
        int pos16 = tid >> 4, cc = tid & 15;
        int pos = pos16 & 3;           // slots 0..15 hold pos 0..3 x4 (cols duplicate)
        int m = p0 + pos;
        int c0 = cc * 16;
        int h = c0 >> 6;
        const float* arow = attnf + ((size_t)b * MM2 + m) * 32;
        // bulk-issue all 16 out1 loads + 8 attn loads, then combine+write
        uint4 P0[4], P1[4], Q0[4], Q1[4];
        float a0v[4], a1v[4];
        #pragma unroll
        for (int t = 0; t < 4; ++t) {
            const uint4* r0 = (const uint4*)(out1 + ((size_t)b * MMP + 1 + 8 * m + 2 * t) * 256 + c0);
            const uint4* r1 = (const uint4*)(out1 + ((size_t)b * MMP + 2 + 8 * m + 2 * t) * 256 + c0);
            P0[t] = r0[0]; P1[t] = r0[1];
            Q0[t] = r1[0]; Q1[t] = r1[1];
            a0v[t] = arow[(2 * t) * 4 + h];
            a1v[t] = arow[(2 * t + 1) * 4 + h];
        }
        #pragma unroll
        for (int t = 0; t < 4; ++t) {
            float a0 = a0v[t], a1 = a1v[t];
            u32 w[8];
            {
                u32 pv[4] = {P0[t].x, P0[t].y, P0[t].z, P0[t].w};
                u32 qv[4] = {Q0[t].x, Q0[t].y, Q0[t].z, Q0[t].w};
                #pragma unroll
                for (int e = 0; e < 4; ++e) {
                    float lo = fmaf(bflo(pv[e]), a0, bflo(qv[e]) * a1);
                    float hi = fmaf(bfhi(pv[e]), a0, bfhi(qv[e]) * a1);
                    w[e] = pk(lo, hi);
                }
            }
            {
                u32 pv[4] = {P1[t].x, P1[t].y, P1[t].z, P1[t].w};
                u32 qv[4] = {Q1[t].x, Q1[t].y, Q1[t].z, Q1[t].w};
                #pragma unroll
                for (int e = 0; e < 4; ++e) {
                    float lo = fmaf(bflo(pv[e]), a0, bflo(qv[e]) * a1);
                    float hi = fmaf(bfhi(pv[e]), a0, bfhi(qv[e]) * a1);
                    w[4 + e] = pk(lo, hi);
                }
            }
            u32* dst = (u32*)&aggl[pos16 * 1024 + h * 256 + t * 64 + (c0 & 63)];
            ((uint4*)dst)[0] = make_uint4(w[0], w[1], w[2], w[3]);
            ((uint4*)dst)[1] = make_uint4(w[4], w[5], w[6], w[7]);
        }
    }
    __syncthreads();

    int lane = tid & 63, g = tid >> 6;
    int col = lane & 15, quad = lane >> 4;
    f32x4 accn[4], accs[4];
    #pragma unroll
    for (int mt = 0; mt < 4; ++mt) { accn[mt] = (f32x4){0,0,0,0}; accs[mt] = (f32x4){0,0,0,0}; }

    const u16* wAb = wA2 + (size_t)(g * 8) * 4 * 512 + lane * 8;
    short8 aAc[4];
    #pragma unroll
    for (int mt = 0; mt < 4; ++mt) aAc[mt] = *(const short8*)(wAb + mt * 512);

    #pragma unroll
    for (int kc = 0; kc < 8; ++kc) {
        short8 aAn[4];
        if (kc < 7) {
            #pragma unroll
            for (int mt = 0; mt < 4; ++mt) aAn[mt] = *(const short8*)(wAb + ((kc + 1) * 4 + mt) * 512);
        }
        short8 bB = *(const short8*)&aggl[col * 1024 + g * 256 + kc * 32 + quad * 8];
        #pragma unroll
        for (int mt = 0; mt < 4; ++mt)
            accn[mt] = __builtin_amdgcn_mfma_f32_16x16x32_bf16(aAc[mt], bB, accn[mt], 0, 0, 0);
        if (kc < 7) {
            #pragma unroll
            for (int mt = 0; mt < 4; ++mt) aAc[mt] = aAn[mt];
        }
    }
    {
        int pcol = col & 3;
        #pragma unroll
        for (int kc = 0; kc < 2; ++kc) {
            short8 bS = *(const short8*)(out1 + ((size_t)b * MMP + p0 + pcol) * 256 + g * 64 + kc * 32 + quad * 8);
            #pragma unroll
            for (int mt = 0; mt < 4; ++mt) {
                short8 aS = *(const short8*)(wS2 + (((g * 2 + kc) * 4 + mt) * 512 + lane * 8));
                accs[mt] = __builtin_amdgcn_mfma_f32_16x16x32_bf16(aS, bS, accs[mt], 0, 0, 0);
            }
        }
    }
    __syncthreads();

    float* outt = (float*)shraw;
    float* n2t  = outt + 16 * 268;
    #pragma unroll
    for (int mt = 0; mt < 4; ++mt) {
        #pragma unroll
        for (int r = 0; r < 4; ++r) {
            int o = g * 64 + mt * 16 + quad * 4 + r;
            float n2 = fmaxf(accn[mt][r] + bagg2[o], 0.f);
            float s2 = fmaxf(accs[mt][r] + bsrc2[o], 0.f);
            outt[col * 268 + o] = n2 + s2;
            n2t[col * 268 + o] = n2;
        }
    }
    __syncthreads();

    {
        int pos = tid >> 6, cc = (tid & 63) * 4;
        *(float4*)&outp[((size_t)b * MM2 + p0 + pos) * 256 + cc] = *(const float4*)&outt[pos * 268 + cc];
    }
    if (tid < 64) {
        int pos = tid >> 4, kk = tid & 15;
        const float* grow = gt2 + ((size_t)b * MM2 + p0 + pos) * 256 + kk * 16;
        const float* nrow = n2t + pos * 268 + kk * 16;
        float s = 0.f;
        #pragma unroll
        for (int c = 0; c < 16; ++c) { float d = grow[c] - nrow[c]; s = fmaf(d, d, s); }
        shred[pos * 16 + kk] = s;
    }
    __syncthreads();
    if (tid < 4) {
        float s = 0.f;
        #pragma unroll
        for (int kk = 0; kk < 16; ++kk) s += shred[tid * 16 + kk];
        score2p[(size_t)b * MM2 + p0 + tid] = 1.f - __expf(-0.5f * s);
    }
}

extern "C" void kernel_launch(void* const* d_in, const int* in_sizes, int n_in,
                              void* d_out, int out_size, void* d_ws, size_t ws_size,
                              hipStream_t stream) {
    const float* x     = (const float*)d_in[0];
    const float* gt    = (const float*)d_in[1];
    const float* watt  = (const float*)d_in[2];
    const float* batt  = (const float*)d_in[3];
    const float* wgt1  = (const float*)d_in[4];
    const float* bgt1  = (const float*)d_in[5];
    const float* wgt2  = (const float*)d_in[6];
    const float* bgt2  = (const float*)d_in[7];
    const float* wagg1 = (const float*)d_in[8];
    const float* bagg1 = (const float*)d_in[9];
    const float* wsrc1 = (const float*)d_in[10];
    const float* bsrc1 = (const float*)d_in[11];
    const float* wagg2 = (const float*)d_in[12];
    const float* bagg2 = (const float*)d_in[13];
    const float* wsrc2 = (const float*)d_in[14];
    const float* bsrc2 = (const float*)d_in[15];

    char* ws = (char*)d_ws;
    float* ws_gt2  = (float*)(ws + 0);            // 2 MB
    float* attnf   = (float*)(ws + 2097152);      // 256 KB
    float* n1m0    = (float*)(ws + 2359296);      // 4 KB
    float* gt1m0   = (float*)(ws + 2363392);      // 4 KB
    u16*   wA1     = (u16*)(ws + 2367488);        // 128 KB
    u16*   wS1     = (u16*)(ws + 2498560);        // 32 KB
    u16*   wA2     = (u16*)(ws + 2531328);        // 128 KB
    u16*   wS2     = (u16*)(ws + 2662400);        // 32 KB
    u16*   wattB   = (u16*)(ws + 2695168);        // 8 KB
    u16*   out1    = (u16*)(ws + 2703360);        // 8,421,376 B

    float* outp    = (float*)d_out;               // 2048*256
    float* score1p = outp + 524288;               // 4
    float* score2p = outp + 524292;               // 2048

    setup_k<<<dim3(656), dim3(256), 0, stream>>>(wagg1, wagg2, wsrc1, wsrc2, watt,
                                                 wA1, wA2, wS1, wS2, wattB);
    l1fused_k<<<dim3(321, 4), dim3(256), 0, stream>>>(x, batt, wA1, wS1, wattB, bagg1, bsrc1,
                                                      attnf, out1, n1m0,
                                                      gt, wgt1, bgt1, wgt2, bgt2, ws_gt2, gt1m0);
    l2conv_k<<<dim3(129, 4), dim3(256), 0, stream>>>(out1, attnf, ws_gt2, wA2, wS2, bagg2, bsrc2,
                                                     gt1m0, n1m0, outp, score2p, score1p);
}

// Round 6
// 260.213 us; speedup vs baseline: 1.8372x; 1.8372x over previous
//
#include <hip/hip_runtime.h>
#include <hip/hip_bf16.h>

typedef unsigned short u16;
typedef unsigned int   u32;
typedef __attribute__((ext_vector_type(8))) short short8;
typedef __attribute__((ext_vector_type(4))) float f32x4;

#define BB  4
#define LL  32777
#define MM  4097
#define MMP 4112
#define MM2 512

__device__ __forceinline__ float b2f(u16 u) { return __uint_as_float(((u32)u) << 16); }
__device__ __forceinline__ u16 f2bf(float f) {           // cold path only (setup swizzles)
    u32 u = __float_as_uint(f);
    return (u16)((u + 0x7fffu + ((u >> 16) & 1u)) >> 16);   // RNE
}
// HW v_cvt_pk_bf16_f32 (RNE) — a in low 16, b in high 16
__device__ __forceinline__ u32 pk(float a, float b) {
    union { __hip_bfloat162 h; u32 u; } cv;
    cv.h = __float22bfloat162_rn(make_float2(a, b));
    return cv.u;
}
__device__ __forceinline__ float bflo(u32 u) { return __uint_as_float(u << 16); }
__device__ __forceinline__ float bfhi(u32 u) { return __uint_as_float(u & 0xffff0000u); }

// ---------- setup: weight swizzles only ----------
__global__ __launch_bounds__(256) void setup_k(
    const float* __restrict__ wagg1, const float* __restrict__ wagg2,
    const float* __restrict__ wsrc1, const float* __restrict__ wsrc2,
    const float* __restrict__ watt,
    u16* __restrict__ wA1, u16* __restrict__ wA2,
    u16* __restrict__ wS1, u16* __restrict__ wS2, u16* __restrict__ wattB) {
    int idx = blockIdx.x * 256 + threadIdx.x;      // 0..167935
    if (idx < 131072) {
        int which = idx >> 16;
        int e = idx & 65535;
        int j = e & 7, lane = (e >> 3) & 63, mt = (e >> 9) & 3, kc = (e >> 11) & 7, g = (e >> 14) & 3;
        int ol = mt * 16 + (lane & 15);
        int k = kc * 32 + (lane >> 4) * 8 + j;
        int t = k >> 6, ci = k & 63;
        const float* src = which ? wagg2 : wagg1;
        u16* dst = which ? wA2 : wA1;
        dst[e] = f2bf(src[(g * 64 + ol) * 256 + ci * 4 + t]);
    } else if (idx < 163840) {
        int e2 = idx - 131072;
        int which = e2 >> 14;
        int e = e2 & 16383;
        int j = e & 7, lane = (e >> 3) & 63, mt = (e >> 9) & 3, kc = (e >> 11) & 1, g = (e >> 12) & 3;
        int ol = mt * 16 + (lane & 15);
        int k = kc * 32 + (lane >> 4) * 8 + j;
        const float* src = which ? wsrc2 : wsrc1;
        u16* dst = which ? wS2 : wS1;
        dst[e] = f2bf(src[(g * 64 + ol) * 64 + k]);
    } else {
        int e = idx - 163840;                      // 0..4095
        int j = e & 7, lane = (e >> 3) & 63, kc = e >> 9;
        int h = lane & 15, quad = lane >> 4;
        int k = kc * 32 + quad * 8 + j;
        wattB[e] = (h < 4) ? f2bf(watt[k * 4 + h]) : (u16)0;
    }
}

// ---------- fused layer1 (x>=64, 4-pos tiles) + gt double-GEMM (x<64) ----------
// 4-position tiles: LDS ~19 KB -> 6 blocks/CU (24 waves) vs 4 blocks at 8-pos.
__global__ __launch_bounds__(256, 6) void l1fused_k(
    const float* __restrict__ x, const float* __restrict__ batt,
    const u16* __restrict__ wA1, const u16* __restrict__ wS1,
    const u16* __restrict__ wattB,
    const float* __restrict__ bagg1, const float* __restrict__ bsrc1,
    float* __restrict__ attnf, u16* __restrict__ out1, float* __restrict__ n1m0,
    const float* __restrict__ gt, const float* __restrict__ W1, const float* __restrict__ b1,
    const float* __restrict__ W2, const float* __restrict__ b2,
    float* __restrict__ gt2, float* __restrict__ gt1m0) {
    __shared__ u16   sh_node[32 * 256];    // [r=pos*8+n][cb^((pos^n)&7)] bf16, 16 KB
    __shared__ u16   sh_srcq[4 * 256];     // [q][cb^q] bf16, 2 KB; aliased as out tile
    __shared__ float shR[144];             // rdN[0..127], rdS[128..143]

    int tid = threadIdx.x;
    int b = blockIdx.y;

    if (blockIdx.x < 64) {
        // ---- fused gt GEMM: gt1 in LDS, gt2 to global ----
        float (*sh)[8] = (float(*)[8])sh_node;     // 8 KB alias
        int gi = blockIdx.x * 4 + b;               // 0..255
        int row0 = gi * 8;
        {
            int r = tid >> 5, j = tid & 31;
            const float4* a4 = (const float4*)(gt + (size_t)(row0 + r) * 256 + j * 8);
            float4 v0 = a4[0], v1 = a4[1];
            sh[j * 8 + 0][r] = v0.x; sh[j * 8 + 1][r] = v0.y;
            sh[j * 8 + 2][r] = v0.z; sh[j * 8 + 3][r] = v0.w;
            sh[j * 8 + 4][r] = v1.x; sh[j * 8 + 5][r] = v1.y;
            sh[j * 8 + 6][r] = v1.z; sh[j * 8 + 7][r] = v1.w;
        }
        __syncthreads();
        int o = tid;
        float acc[8];
        {
            float bo = b1[o];
            #pragma unroll
            for (int i = 0; i < 8; ++i) acc[i] = bo;
        }
        #pragma unroll 16
        for (int k = 0; k < 256; ++k) {
            float wv = W1[k * 256 + o];
            const float4* ap = (const float4*)&sh[k][0];
            float4 a0 = ap[0], a1 = ap[1];
            acc[0] = fmaf(a0.x, wv, acc[0]); acc[1] = fmaf(a0.y, wv, acc[1]);
            acc[2] = fmaf(a0.z, wv, acc[2]); acc[3] = fmaf(a0.w, wv, acc[3]);
            acc[4] = fmaf(a1.x, wv, acc[4]); acc[5] = fmaf(a1.y, wv, acc[5]);
            acc[6] = fmaf(a1.z, wv, acc[6]); acc[7] = fmaf(a1.w, wv, acc[7]);
        }
        #pragma unroll
        for (int i = 0; i < 8; ++i) acc[i] = fmaxf(acc[i], 0.f);
        if ((row0 & 511) == 0) gt1m0[(row0 >> 9) * 256 + o] = acc[0];
        __syncthreads();
        #pragma unroll
        for (int i = 0; i < 8; ++i) sh[o][i] = acc[i];
        __syncthreads();
        {
            float bo = b2[o];
            #pragma unroll
            for (int i = 0; i < 8; ++i) acc[i] = bo;
        }
        #pragma unroll 16
        for (int k = 0; k < 256; ++k) {
            float wv = W2[k * 256 + o];
            const float4* ap = (const float4*)&sh[k][0];
            float4 a0 = ap[0], a1 = ap[1];
            acc[0] = fmaf(a0.x, wv, acc[0]); acc[1] = fmaf(a0.y, wv, acc[1]);
            acc[2] = fmaf(a0.z, wv, acc[2]); acc[3] = fmaf(a0.w, wv, acc[3]);
            acc[4] = fmaf(a1.x, wv, acc[4]); acc[5] = fmaf(a1.y, wv, acc[5]);
            acc[6] = fmaf(a1.z, wv, acc[6]); acc[7] = fmaf(a1.w, wv, acc[7]);
        }
        #pragma unroll
        for (int i = 0; i < 8; ++i) gt2[(size_t)(row0 + i) * 256 + o] = fmaxf(acc[i], 0.f);
        return;
    }

    int bx = blockIdx.x - 64;      // 0..1024
    int lane = tid & 63, w = tid >> 6;
    int quad = lane >> 4;
    int p0 = bx * 4;

    // stage x slab: 32 node rows + 4 src rows, 3 passes, 12 float4/thread.
    // Compiler-visible loads, converted+written immediately (spill-safe).
    {
        int rslot = tid >> 4, cseg = tid & 15;
        const float* xb = x + (size_t)b * LL * 256;
        const float4* sp[3];
        u16* dstA[3];
        int keyA[3];
        bool valA[3];
        #pragma unroll
        for (int pass = 0; pass < 3; ++pass) {
            int r = pass * 16 + rslot;
            int grow, key; u16* dst; bool val = true;
            if (r < 32) {
                int pos = r >> 3, nn = r & 7;
                int gp = p0 + pos; int gpc = gp < MM ? gp : MM - 1;
                grow = 1 + 8 * gpc + nn;
                key = (pos ^ nn) & 7;
                dst = sh_node + r * 256;
            } else {
                int q = r - 32;
                val = (q < 4);
                int qq = q < 4 ? q : 3;
                int gp = p0 + qq; int gpc = gp < MM ? gp : MM - 1;
                grow = gpc;
                key = qq;
                dst = sh_srcq + qq * 256;
            }
            sp[pass] = (const float4*)(xb + (size_t)grow * 256 + cseg * 16);
            dstA[pass] = dst; keyA[pass] = key; valA[pass] = val;
        }
        float4 v0[3], v1[3], v2[3], v3[3];
        #pragma unroll
        for (int pass = 0; pass < 3; ++pass) {
            v0[pass] = sp[pass][0]; v1[pass] = sp[pass][1];
            v2[pass] = sp[pass][2]; v3[pass] = sp[pass][3];
        }
        #pragma unroll
        for (int pass = 0; pass < 3; ++pass) {
            if (valA[pass]) {
                uint4 o0, o1;
                o0.x = pk(v0[pass].x, v0[pass].y); o0.y = pk(v0[pass].z, v0[pass].w);
                o0.z = pk(v1[pass].x, v1[pass].y); o0.w = pk(v1[pass].z, v1[pass].w);
                o1.x = pk(v2[pass].x, v2[pass].y); o1.y = pk(v2[pass].z, v2[pass].w);
                o1.z = pk(v3[pass].x, v3[pass].y); o1.w = pk(v3[pass].z, v3[pass].w);
                int cb0 = cseg * 2, key = keyA[pass];
                *(uint4*)(dstA[pass] + ((cb0 ^ key) * 8))       = o0;
                *(uint4*)(dstA[pass] + (((cb0 + 1) ^ key) * 8)) = o1;
            }
        }
    }
    // wattB loads before the barrier: L2 latency drains under it
    short8 wB[8];
    #pragma unroll
    for (int kc = 0; kc < 8; ++kc) wB[kc] = *(const short8*)(wattB + kc * 512 + lane * 8);
    float battw = batt[w];
    __syncthreads();

    // phase 1: rowdots via MFMA. waves 0-1: node tiles; wave 2: src; wave 3 idle.
    {
        int m = lane & 15;
        int h = lane & 15;
        if (w < 2) {
            int r = w * 16 + m;
            int key = ((r >> 3) ^ (r & 7)) & 7;
            const u16* rowp = sh_node + r * 256;
            f32x4 acc = (f32x4){0.f, 0.f, 0.f, 0.f};
            #pragma unroll
            for (int kc = 0; kc < 8; ++kc) {
                int cb = kc * 4 + quad;
                short8 aF = *(const short8*)(rowp + ((cb ^ key) * 8));
                acc = __builtin_amdgcn_mfma_f32_16x16x32_bf16(aF, wB[kc], acc, 0, 0, 0);
            }
            if (h < 4) {
                #pragma unroll
                for (int r2 = 0; r2 < 4; ++r2)
                    shR[(w * 16 + quad * 4 + r2) * 4 + h] = acc[r2];
            }
        } else if (w == 2) {
            int ms = m < 4 ? m : 3;
            int key = ms;
            const u16* rowp = sh_srcq + ms * 256;
            f32x4 acc = (f32x4){0.f, 0.f, 0.f, 0.f};
            #pragma unroll
            for (int kc = 0; kc < 8; ++kc) {
                int cb = kc * 4 + quad;
                short8 aF = *(const short8*)(rowp + ((cb ^ key) * 8));
                acc = __builtin_amdgcn_mfma_f32_16x16x32_bf16(aF, wB[kc], acc, 0, 0, 0);
            }
            if (h < 4) {
                #pragma unroll
                for (int r2 = 0; r2 < 4; ++r2) {
                    int rr = quad * 4 + r2;
                    if (rr < 4) shR[128 + rr * 4 + h] = acc[r2];
                }
            }
        }
    }
    __syncthreads();

    // softmax per-lane (q=pos, h=g) straight into registers
    int g = w;
    int col = lane & 15;
    int pos = col & 3;
    float aT[8];
    {
        float base = shR[128 + pos * 4 + g] + battw;
        float l[8], mx = -3.0e38f;
        #pragma unroll
        for (int n = 0; n < 8; ++n) { l[n] = shR[(pos * 8 + n) * 4 + g] + base; mx = fmaxf(mx, l[n]); }
        float s = 0.f;
        #pragma unroll
        for (int n = 0; n < 8; ++n) { l[n] = __expf(l[n] - mx); s += l[n]; }
        float inv = 1.f / s;
        #pragma unroll
        for (int n = 0; n < 8; ++n) aT[n] = l[n] * inv;
        int gp = p0 + pos;
        if (quad == 0 && col < 4 && gp < MM2) {
            #pragma unroll
            for (int n = 0; n < 8; ++n)
                attnf[(((size_t)b * MM2 + gp) * 8 + n) * 4 + g] = aT[n];
        }
    }

    // phase 3a: node conv MFMA
    f32x4 accn[4];
    #pragma unroll
    for (int mt = 0; mt < 4; ++mt) accn[mt] = (f32x4){0, 0, 0, 0};
    const u16* wAb = wA1 + (size_t)(g * 8) * 4 * 512 + lane * 8;
    #pragma unroll
    for (int kc = 0; kc < 8; ++kc) {
        int k0 = kc * 32 + quad * 8;
        int t = k0 >> 6, ci0 = k0 & 63;
        int cb = (g * 64 + ci0) >> 3;
        int r0 = pos * 8 + 2 * t;
        int key0 = (pos ^ (2 * t)) & 7, key1 = (pos ^ (2 * t + 1)) & 7;
        short8 n0 = *(const short8*)(sh_node + r0 * 256 + ((cb ^ key0) * 8));
        short8 n1 = *(const short8*)(sh_node + (r0 + 1) * 256 + ((cb ^ key1) * 8));
        float a0 = aT[2 * t], a1 = aT[2 * t + 1];
        union { uint4 u; short8 s; } cv;
        #pragma unroll
        for (int e = 0; e < 4; ++e) {
            float lo = fmaf(a0, b2f((u16)n0[2 * e]),     a1 * b2f((u16)n1[2 * e]));
            float hi = fmaf(a0, b2f((u16)n0[2 * e + 1]), a1 * b2f((u16)n1[2 * e + 1]));
            ((u32*)&cv.u)[e] = pk(lo, hi);
        }
        short8 bB = cv.s;
        #pragma unroll
        for (int mt = 0; mt < 4; ++mt) {
            short8 aA = *(const short8*)(wAb + (kc * 4 + mt) * 512);
            accn[mt] = __builtin_amdgcn_mfma_f32_16x16x32_bf16(aA, bB, accn[mt], 0, 0, 0);
        }
    }
    // phase 3b: src conv MFMA
    f32x4 accs[4];
    #pragma unroll
    for (int mt = 0; mt < 4; ++mt) accs[mt] = (f32x4){0, 0, 0, 0};
    #pragma unroll
    for (int kc = 0; kc < 2; ++kc) {
        int cb = (g * 64 + kc * 32 + quad * 8) >> 3;
        short8 bS = *(const short8*)(sh_srcq + pos * 256 + ((cb ^ pos) * 8));
        #pragma unroll
        for (int mt = 0; mt < 4; ++mt) {
            short8 aS = *(const short8*)(wS1 + (((g * 2 + kc) * 4 + mt) * 512 + lane * 8));
            accs[mt] = __builtin_amdgcn_mfma_f32_16x16x32_bf16(aS, bS, accs[mt], 0, 0, 0);
        }
    }
    __syncthreads();   // src reads done; reuse sh_srcq as out tile [pos][o]

    u16* outt = sh_srcq;
    #pragma unroll
    for (int mt = 0; mt < 4; ++mt) {
        int ob = g * 64 + mt * 16 + quad * 4;
        float v[4], n1v[4];
        #pragma unroll
        for (int r = 0; r < 4; ++r) {
            int o = ob + r;
            float n1 = fmaxf(accn[mt][r] + bagg1[o], 0.f);
            float s1 = fmaxf(accs[mt][r] + bsrc1[o], 0.f);
            n1v[r] = n1;
            v[r] = n1 + s1;
        }
        if (col < 4) {
            u32* wp = (u32*)&outt[col * 256 + ob];
            wp[0] = pk(v[0], v[1]);
            wp[1] = pk(v[2], v[3]);
        }
        if (bx == 0 && col == 0) {
            #pragma unroll
            for (int r = 0; r < 4; ++r) n1m0[b * 256 + ob + r] = n1v[r];
        }
    }
    __syncthreads();
    if (tid < 128) {
        int posw = tid >> 5, cc = (tid & 31) * 8;
        if (p0 + posw < MM)
            *(uint4*)&out1[((size_t)b * MMP + p0 + posw) * 256 + cc] = *(const uint4*)&outt[posw * 256 + cc];
    }
}

// ---------- layer2 conv + score2 (blocks x<128, 4 pos each) + score1 (x==128) ----------
__global__ __launch_bounds__(256) void l2conv_k(
    const u16* __restrict__ out1, const float* __restrict__ attnf,
    const float* __restrict__ gt2,
    const u16* __restrict__ wA2, const u16* __restrict__ wS2,
    const float* __restrict__ bagg2, const float* __restrict__ bsrc2,
    const float* __restrict__ gt1m0, const float* __restrict__ n1m0,
    float* __restrict__ outp, float* __restrict__ score2p, float* __restrict__ score1p) {
    __shared__ char shraw[16 * 268 * 4 * 2];
    __shared__ float shred[128];

    int tid = threadIdx.x;
    int b = blockIdx.y;

    if (blockIdx.x == 128) {            // fused score1
        float d = gt1m0[b * 256 + tid] - n1m0[b * 256 + tid];
        float v = d * d;
        #pragma unroll
        for (int off = 32; off > 0; off >>= 1) v += __shfl_down(v, off, 64);
        if ((tid & 63) == 0) shred[tid >> 6] = v;
        __syncthreads();
        if (tid == 0) score1p[b] = 1.f - __expf(-0.5f * (shred[0] + shred[1] + shred[2] + shred[3]));
        return;
    }

    int p0 = blockIdx.x * 4;           // 4 positions per block
    u16* aggl = (u16*)shraw;

    {
        int pos16 = tid >> 4, cc = tid & 15;
        int pos = pos16 & 3;           // slots 0..15 hold pos 0..3 x4 (cols duplicate)
        int m = p0 + pos;
        int c0 = cc * 16;
        int h = c0 >> 6;
        const float* arow = attnf + ((size_t)b * MM2 + m) * 32;
        // bulk-issue all 16 out1 loads + 8 attn loads, then combine+write
        uint4 P0[4], P1[4], Q0[4], Q1[4];
        float a0v[4], a1v[4];
        #pragma unroll
        for (int t = 0; t < 4; ++t) {
            const uint4* r0 = (const uint4*)(out1 + ((size_t)b * MMP + 1 + 8 * m + 2 * t) * 256 + c0);
            const uint4* r1 = (const uint4*)(out1 + ((size_t)b * MMP + 2 + 8 * m + 2 * t) * 256 + c0);
            P0[t] = r0[0]; P1[t] = r0[1];
            Q0[t] = r1[0]; Q1[t] = r1[1];
            a0v[t] = arow[(2 * t) * 4 + h];
            a1v[t] = arow[(2 * t + 1) * 4 + h];
        }
        #pragma unroll
        for (int t = 0; t < 4; ++t) {
            float a0 = a0v[t], a1 = a1v[t];
            u32 w[8];
            {
                u32 pv[4] = {P0[t].x, P0[t].y, P0[t].z, P0[t].w};
                u32 qv[4] = {Q0[t].x, Q0[t].y, Q0[t].z, Q0[t].w};
                #pragma unroll
                for (int e = 0; e < 4; ++e) {
                    float lo = fmaf(bflo(pv[e]), a0, bflo(qv[e]) * a1);
                    float hi = fmaf(bfhi(pv[e]), a0, bfhi(qv[e]) * a1);
                    w[e] = pk(lo, hi);
                }
            }
            {
                u32 pv[4] = {P1[t].x, P1[t].y, P1[t].z, P1[t].w};
                u32 qv[4] = {Q1[t].x, Q1[t].y, Q1[t].z, Q1[t].w};
                #pragma unroll
                for (int e = 0; e < 4; ++e) {
                    float lo = fmaf(bflo(pv[e]), a0, bflo(qv[e]) * a1);
                    float hi = fmaf(bfhi(pv[e]), a0, bfhi(qv[e]) * a1);
                    w[4 + e] = pk(lo, hi);
                }
            }
            u32* dst = (u32*)&aggl[pos16 * 1024 + h * 256 + t * 64 + (c0 & 63)];
            ((uint4*)dst)[0] = make_uint4(w[0], w[1], w[2], w[3]);
            ((uint4*)dst)[1] = make_uint4(w[4], w[5], w[6], w[7]);
        }
    }
    __syncthreads();

    int lane = tid & 63, g = tid >> 6;
    int col = lane & 15, quad = lane >> 4;
    f32x4 accn[4], accs[4];
    #pragma unroll
    for (int mt = 0; mt < 4; ++mt) { accn[mt] = (f32x4){0,0,0,0}; accs[mt] = (f32x4){0,0,0,0}; }

    const u16* wAb = wA2 + (size_t)(g * 8) * 4 * 512 + lane * 8;
    short8 aAc[4];
    #pragma unroll
    for (int mt = 0; mt < 4; ++mt) aAc[mt] = *(const short8*)(wAb + mt * 512);

    #pragma unroll
    for (int kc = 0; kc < 8; ++kc) {
        short8 aAn[4];
        if (kc < 7) {
            #pragma unroll
            for (int mt = 0; mt < 4; ++mt) aAn[mt] = *(const short8*)(wAb + ((kc + 1) * 4 + mt) * 512);
        }
        short8 bB = *(const short8*)&aggl[col * 1024 + g * 256 + kc * 32 + quad * 8];
        #pragma unroll
        for (int mt = 0; mt < 4; ++mt)
            accn[mt] = __builtin_amdgcn_mfma_f32_16x16x32_bf16(aAc[mt], bB, accn[mt], 0, 0, 0);
        if (kc < 7) {
            #pragma unroll
            for (int mt = 0; mt < 4; ++mt) aAc[mt] = aAn[mt];
        }
    }
    {
        int pcol = col & 3;
        #pragma unroll
        for (int kc = 0; kc < 2; ++kc) {
            short8 bS = *(const short8*)(out1 + ((size_t)b * MMP + p0 + pcol) * 256 + g * 64 + kc * 32 + quad * 8);
            #pragma unroll
            for (int mt = 0; mt < 4; ++mt) {
                short8 aS = *(const short8*)(wS2 + (((g * 2 + kc) * 4 + mt) * 512 + lane * 8));
                accs[mt] = __builtin_amdgcn_mfma_f32_16x16x32_bf16(aS, bS, accs[mt], 0, 0, 0);
            }
        }
    }
    __syncthreads();

    float* outt = (float*)shraw;
    float* n2t  = outt + 16 * 268;
    #pragma unroll
    for (int mt = 0; mt < 4; ++mt) {
        #pragma unroll
        for (int r = 0; r < 4; ++r) {
            int o = g * 64 + mt * 16 + quad * 4 + r;
            float n2 = fmaxf(accn[mt][r] + bagg2[o], 0.f);
            float s2 = fmaxf(accs[mt][r] + bsrc2[o], 0.f);
            outt[col * 268 + o] = n2 + s2;
            n2t[col * 268 + o] = n2;
        }
    }
    __syncthreads();

    {
        int pos = tid >> 6, cc = (tid & 63) * 4;
        *(float4*)&outp[((size_t)b * MM2 + p0 + pos) * 256 + cc] = *(const float4*)&outt[pos * 268 + cc];
    }
    if (tid < 64) {
        int pos = tid >> 4, kk = tid & 15;
        const float* grow = gt2 + ((size_t)b * MM2 + p0 + pos) * 256 + kk * 16;
        const float* nrow = n2t + pos * 268 + kk * 16;
        float s = 0.f;
        #pragma unroll
        for (int c = 0; c < 16; ++c) { float d = grow[c] - nrow[c]; s = fmaf(d, d, s); }
        shred[pos * 16 + kk] = s;
    }
    __syncthreads();
    if (tid < 4) {
        float s = 0.f;
        #pragma unroll
        for (int kk = 0; kk < 16; ++kk) s += shred[tid * 16 + kk];
        score2p[(size_t)b * MM2 + p0 + tid] = 1.f - __expf(-0.5f * s);
    }
}

extern "C" void kernel_launch(void* const* d_in, const int* in_sizes, int n_in,
                              void* d_out, int out_size, void* d_ws, size_t ws_size,
                              hipStream_t stream) {
    const float* x     = (const float*)d_in[0];
    const float* gt    = (const float*)d_in[1];
    const float* watt  = (const float*)d_in[2];
    const float* batt  = (const float*)d_in[3];
    const float* wgt1  = (const float*)d_in[4];
    const float* bgt1  = (const float*)d_in[5];
    const float* wgt2  = (const float*)d_in[6];
    const float* bgt2  = (const float*)d_in[7];
    const float* wagg1 = (const float*)d_in[8];
    const float* bagg1 = (const float*)d_in[9];
    const float* wsrc1 = (const float*)d_in[10];
    const float* bsrc1 = (const float*)d_in[11];
    const float* wagg2 = (const float*)d_in[12];
    const float* bagg2 = (const float*)d_in[13];
    const float* wsrc2 = (const float*)d_in[14];
    const float* bsrc2 = (const float*)d_in[15];

    char* ws = (char*)d_ws;
    float* ws_gt2  = (float*)(ws + 0);            // 2 MB
    float* attnf   = (float*)(ws + 2097152);      // 256 KB
    float* n1m0    = (float*)(ws + 2359296);      // 4 KB
    float* gt1m0   = (float*)(ws + 2363392);      // 4 KB
    u16*   wA1     = (u16*)(ws + 2367488);        // 128 KB
    u16*   wS1     = (u16*)(ws + 2498560);        // 32 KB
    u16*   wA2     = (u16*)(ws + 2531328);        // 128 KB
    u16*   wS2     = (u16*)(ws + 2662400);        // 32 KB
    u16*   wattB   = (u16*)(ws + 2695168);        // 8 KB
    u16*   out1    = (u16*)(ws + 2703360);        // 8,421,376 B

    float* outp    = (float*)d_out;               // 2048*256
    float* score1p = outp + 524288;               // 4
    float* score2p = outp + 524292;               // 2048

    setup_k<<<dim3(656), dim3(256), 0, stream>>>(wagg1, wagg2, wsrc1, wsrc2, watt,
                                                 wA1, wA2, wS1, wS2, wattB);
    l1fused_k<<<dim3(1089, 4), dim3(256), 0, stream>>>(x, batt, wA1, wS1, wattB, bagg1, bsrc1,
                                                       attnf, out1, n1m0,
                                                       gt, wgt1, bgt1, wgt2, bgt2, ws_gt2, gt1m0);
    l2conv_k<<<dim3(129, 4), dim3(256), 0, stream>>>(out1, attnf, ws_gt2, wA2, wS2, bagg2, bsrc2,
                                                     gt1m0, n1m0, outp, score2p, score1p);
}

// Round 8
// 245.880 us; speedup vs baseline: 1.9443x; 1.0583x over previous
//
#include <hip/hip_runtime.h>
#include <hip/hip_bf16.h>

typedef unsigned short u16;
typedef unsigned int   u32;
typedef __attribute__((ext_vector_type(8))) short short8;
typedef __attribute__((ext_vector_type(4))) float f32x4;

#define BB  4
#define LL  32777
#define MM  4097
#define MMP 4112
#define MM2 512

__device__ __forceinline__ float b2f(u16 u) { return __uint_as_float(((u32)u) << 16); }
__device__ __forceinline__ u16 f2bf(float f) {           // cold path only (setup swizzles)
    u32 u = __float_as_uint(f);
    return (u16)((u + 0x7fffu + ((u >> 16) & 1u)) >> 16);   // RNE
}
// HW v_cvt_pk_bf16_f32 (RNE) — a in low 16, b in high 16
__device__ __forceinline__ u32 pk(float a, float b) {
    union { __hip_bfloat162 h; u32 u; } cv;
    cv.h = __float22bfloat162_rn(make_float2(a, b));
    return cv.u;
}
__device__ __forceinline__ float bflo(u32 u) { return __uint_as_float(u << 16); }
__device__ __forceinline__ float bfhi(u32 u) { return __uint_as_float(u & 0xffff0000u); }

// ---------- setup: weight swizzles only ----------
__global__ __launch_bounds__(256) void setup_k(
    const float* __restrict__ wagg1, const float* __restrict__ wagg2,
    const float* __restrict__ wsrc1, const float* __restrict__ wsrc2,
    const float* __restrict__ watt,
    u16* __restrict__ wA1, u16* __restrict__ wA2,
    u16* __restrict__ wS1, u16* __restrict__ wS2, u16* __restrict__ wattB) {
    int idx = blockIdx.x * 256 + threadIdx.x;      // 0..167935
    if (idx < 131072) {
        int which = idx >> 16;
        int e = idx & 65535;
        int j = e & 7, lane = (e >> 3) & 63, mt = (e >> 9) & 3, kc = (e >> 11) & 7, g = (e >> 14) & 3;
        int ol = mt * 16 + (lane & 15);
        int k = kc * 32 + (lane >> 4) * 8 + j;
        int t = k >> 6, ci = k & 63;
        const float* src = which ? wagg2 : wagg1;
        u16* dst = which ? wA2 : wA1;
        dst[e] = f2bf(src[(g * 64 + ol) * 256 + ci * 4 + t]);
    } else if (idx < 163840) {
        int e2 = idx - 131072;
        int which = e2 >> 14;
        int e = e2 & 16383;
        int j = e & 7, lane = (e >> 3) & 63, mt = (e >> 9) & 3, kc = (e >> 11) & 1, g = (e >> 12) & 3;
        int ol = mt * 16 + (lane & 15);
        int k = kc * 32 + (lane >> 4) * 8 + j;
        const float* src = which ? wsrc2 : wsrc1;
        u16* dst = which ? wS2 : wS1;
        dst[e] = f2bf(src[(g * 64 + ol) * 64 + k]);
    } else {
        int e = idx - 163840;                      // 0..4095
        int j = e & 7, lane = (e >> 3) & 63, kc = e >> 9;
        int h = lane & 15, quad = lane >> 4;
        int k = kc * 32 + quad * 8 + j;
        wattB[e] = (h < 4) ? f2bf(watt[k * 4 + h]) : (u16)0;
    }
}

// ---------- fused layer1 (x>=64) + gt double-GEMM (x<64), 4 blocks/CU ----------
__global__ __launch_bounds__(256, 4) void l1fused_k(
    const float* __restrict__ x, const float* __restrict__ batt,
    const u16* __restrict__ wA1, const u16* __restrict__ wS1,
    const u16* __restrict__ wattB,
    const float* __restrict__ bagg1, const float* __restrict__ bsrc1,
    float* __restrict__ attnf, u16* __restrict__ out1, float* __restrict__ n1m0,
    const float* __restrict__ gt, const float* __restrict__ W1, const float* __restrict__ b1,
    const float* __restrict__ W2, const float* __restrict__ b2,
    float* __restrict__ gt2, float* __restrict__ gt1m0) {
    __shared__ u16   sh_node[64 * 256];    // [r=pos*8+n][cb^((pos^n)&7)] bf16, 32 KB
    __shared__ u16   sh_srcq[8 * 256];     // [q][cb^(q&7)] bf16, 4 KB; aliased as out tile
    __shared__ float shR[320];             // rdN[0..255], rdS[256..319]

    int tid = threadIdx.x;
    int b = blockIdx.y;

    if (blockIdx.x < 64) {
        // ---- fused gt GEMM: gt1 in LDS, gt2 to global ----
        float (*sh)[8] = (float(*)[8])sh_node;     // 8 KB alias
        int gi = blockIdx.x * 4 + b;               // 0..255
        int row0 = gi * 8;
        {
            int r = tid >> 5, j = tid & 31;
            const float4* a4 = (const float4*)(gt + (size_t)(row0 + r) * 256 + j * 8);
            float4 v0 = a4[0], v1 = a4[1];
            sh[j * 8 + 0][r] = v0.x; sh[j * 8 + 1][r] = v0.y;
            sh[j * 8 + 2][r] = v0.z; sh[j * 8 + 3][r] = v0.w;
            sh[j * 8 + 4][r] = v1.x; sh[j * 8 + 5][r] = v1.y;
            sh[j * 8 + 6][r] = v1.z; sh[j * 8 + 7][r] = v1.w;
        }
        __syncthreads();
        int o = tid;
        float acc[8];
        {
            float bo = b1[o];
            #pragma unroll
            for (int i = 0; i < 8; ++i) acc[i] = bo;
        }
        #pragma unroll 16
        for (int k = 0; k < 256; ++k) {
            float wv = W1[k * 256 + o];
            const float4* ap = (const float4*)&sh[k][0];
            float4 a0 = ap[0], a1 = ap[1];
            acc[0] = fmaf(a0.x, wv, acc[0]); acc[1] = fmaf(a0.y, wv, acc[1]);
            acc[2] = fmaf(a0.z, wv, acc[2]); acc[3] = fmaf(a0.w, wv, acc[3]);
            acc[4] = fmaf(a1.x, wv, acc[4]); acc[5] = fmaf(a1.y, wv, acc[5]);
            acc[6] = fmaf(a1.z, wv, acc[6]); acc[7] = fmaf(a1.w, wv, acc[7]);
        }
        #pragma unroll
        for (int i = 0; i < 8; ++i) acc[i] = fmaxf(acc[i], 0.f);
        if ((row0 & 511) == 0) gt1m0[(row0 >> 9) * 256 + o] = acc[0];
        __syncthreads();
        #pragma unroll
        for (int i = 0; i < 8; ++i) sh[o][i] = acc[i];
        __syncthreads();
        {
            float bo = b2[o];
            #pragma unroll
            for (int i = 0; i < 8; ++i) acc[i] = bo;
        }
        #pragma unroll 16
        for (int k = 0; k < 256; ++k) {
            float wv = W2[k * 256 + o];
            const float4* ap = (const float4*)&sh[k][0];
            float4 a0 = ap[0], a1 = ap[1];
            acc[0] = fmaf(a0.x, wv, acc[0]); acc[1] = fmaf(a0.y, wv, acc[1]);
            acc[2] = fmaf(a0.z, wv, acc[2]); acc[3] = fmaf(a0.w, wv, acc[3]);
            acc[4] = fmaf(a1.x, wv, acc[4]); acc[5] = fmaf(a1.y, wv, acc[5]);
            acc[6] = fmaf(a1.z, wv, acc[6]); acc[7] = fmaf(a1.w, wv, acc[7]);
        }
        #pragma unroll
        for (int i = 0; i < 8; ++i) gt2[(size_t)(row0 + i) * 256 + o] = fmaxf(acc[i], 0.f);
        return;
    }

    int bx = blockIdx.x - 64;      // 0..512
    int lane = tid & 63, w = tid >> 6;
    int quad = lane >> 4;
    int p0 = bx * 8;

    // stage x slab. Inline-asm forces ALL 20 float4 loads in flight (compiler
    // cannot sink volatile asm); single vmcnt(0) + sched_barrier, then convert.
    {
        int rslot = tid >> 4, cseg = tid & 15;
        const float* xb = x + (size_t)b * LL * 256;
        const float* srcA[5];
        u16* dstA[5];
        int keyA[5];
        #pragma unroll
        for (int pass = 0; pass < 5; ++pass) {
            int r = pass * 16 + rslot;
            int grow, key; u16* dst;
            if (r < 64) {
                int pos = r >> 3, nn = r & 7;
                int gp = p0 + pos; int gpc = gp < MM ? gp : MM - 1;
                grow = 1 + 8 * gpc + nn;
                dst = sh_node + r * 256;
                key = (pos ^ nn) & 7;
            } else {
                int q = r - 64;
                int qq = q < 8 ? q : 7;            // clamp: invalid lanes load a safe row
                int gp = p0 + qq; int gpc = gp < MM ? gp : MM - 1;
                grow = gpc;
                dst = sh_srcq + qq * 256;
                key = qq & 7;
            }
            srcA[pass] = xb + (size_t)grow * 256 + cseg * 16;
            dstA[pass] = dst;
            keyA[pass] = key;
        }
        float4 v0[5], v1[5], v2[5], v3[5];
        #pragma unroll
        for (int pass = 0; pass < 5; ++pass) {
            asm volatile("global_load_dwordx4 %0, %1, off"           : "=v"(v0[pass]) : "v"(srcA[pass]));
            asm volatile("global_load_dwordx4 %0, %1, off offset:16" : "=v"(v1[pass]) : "v"(srcA[pass]));
            asm volatile("global_load_dwordx4 %0, %1, off offset:32" : "=v"(v2[pass]) : "v"(srcA[pass]));
            asm volatile("global_load_dwordx4 %0, %1, off offset:48" : "=v"(v3[pass]) : "v"(srcA[pass]));
        }
        asm volatile("s_waitcnt vmcnt(0)" ::: "memory");
        __builtin_amdgcn_sched_barrier(0);
        #pragma unroll
        for (int pass = 0; pass < 5; ++pass) {
            bool val = (pass < 4) || (rslot < 8);
            if (val) {
                uint4 o0, o1;
                o0.x = pk(v0[pass].x, v0[pass].y); o0.y = pk(v0[pass].z, v0[pass].w);
                o0.z = pk(v1[pass].x, v1[pass].y); o0.w = pk(v1[pass].z, v1[pass].w);
                o1.x = pk(v2[pass].x, v2[pass].y); o1.y = pk(v2[pass].z, v2[pass].w);
                o1.z = pk(v3[pass].x, v3[pass].y); o1.w = pk(v3[pass].z, v3[pass].w);
                int cb0 = cseg * 2, key = keyA[pass];
                *(uint4*)(dstA[pass] + ((cb0 ^ key) * 8))       = o0;
                *(uint4*)(dstA[pass] + (((cb0 + 1) ^ key) * 8)) = o1;
            }
        }
    }
    // wattB loads AFTER staging (keeps peak VGPR under the 128 / 4-waves-EU cap);
    // their L2 latency drains under the barrier.
    short8 wB[8];
    #pragma unroll
    for (int kc = 0; kc < 8; ++kc) wB[kc] = *(const short8*)(wattB + kc * 512 + lane * 8);
    float battw = batt[w];
    __syncthreads();

    // phase 1: rowdots via MFMA. wave w: node m-tile w; wave 3 also src tile.
    {
        int m = lane & 15;            // A-frag row within tile
        int h = lane & 15;            // D col (head; valid < 4)
        {
            int r = w * 16 + m;
            int key = ((r >> 3) ^ (r & 7)) & 7;
            const u16* rowp = sh_node + r * 256;
            f32x4 acc = (f32x4){0.f, 0.f, 0.f, 0.f};
            #pragma unroll
            for (int kc = 0; kc < 8; ++kc) {
                int cb = kc * 4 + quad;
                short8 aF = *(const short8*)(rowp + ((cb ^ key) * 8));
                acc = __builtin_amdgcn_mfma_f32_16x16x32_bf16(aF, wB[kc], acc, 0, 0, 0);
            }
            if (h < 4) {
                #pragma unroll
                for (int r2 = 0; r2 < 4; ++r2)
                    shR[(w * 16 + quad * 4 + r2) * 4 + h] = acc[r2];
            }
        }
        if (w == 3) {
            int ms = m < 8 ? m : 7;
            int key = ms & 7;
            const u16* rowp = sh_srcq + ms * 256;
            f32x4 acc = (f32x4){0.f, 0.f, 0.f, 0.f};
            #pragma unroll
            for (int kc = 0; kc < 8; ++kc) {
                int cb = kc * 4 + quad;
                short8 aF = *(const short8*)(rowp + ((cb ^ key) * 8));
                acc = __builtin_amdgcn_mfma_f32_16x16x32_bf16(aF, wB[kc], acc, 0, 0, 0);
            }
            if (h < 4) {
                #pragma unroll
                for (int r2 = 0; r2 < 4; ++r2) {
                    int rr = quad * 4 + r2;
                    if (rr < 8) shR[256 + rr * 4 + h] = acc[r2];
                }
            }
        }
    }
    __syncthreads();

    // phase 2+3 fused: every lane redundantly computes its own softmax (q=pos, h=g)
    // straight into registers — no barrier, no attn LDS round-trip, no idle waves.
    int g = w;
    int col = lane & 15;
    int pos = col & 7;
    float aT[8];
    {
        float base = shR[256 + pos * 4 + g] + battw;
        float l[8], mx = -3.0e38f;
        #pragma unroll
        for (int n = 0; n < 8; ++n) { l[n] = shR[(pos * 8 + n) * 4 + g] + base; mx = fmaxf(mx, l[n]); }
        float s = 0.f;
        #pragma unroll
        for (int n = 0; n < 8; ++n) { l[n] = __expf(l[n] - mx); s += l[n]; }
        float inv = 1.f / s;
        #pragma unroll
        for (int n = 0; n < 8; ++n) aT[n] = l[n] * inv;
        int gp = p0 + pos;
        if (quad == 0 && col < 8 && gp < MM2) {
            #pragma unroll
            for (int n = 0; n < 8; ++n)
                attnf[(((size_t)b * MM2 + gp) * 8 + n) * 4 + g] = aT[n];
        }
    }
    f32x4 accn[4], accs[4];
    #pragma unroll
    for (int mt = 0; mt < 4; ++mt) { accn[mt] = (f32x4){0,0,0,0}; accs[mt] = (f32x4){0,0,0,0}; }

    const u16* wAb = wA1 + (size_t)(g * 8) * 4 * 512 + lane * 8;
    short8 aAc[4];
    #pragma unroll
    for (int mt = 0; mt < 4; ++mt) aAc[mt] = *(const short8*)(wAb + mt * 512);

    #pragma unroll
    for (int kc = 0; kc < 8; ++kc) {
        short8 aAn[4];
        if (kc < 7) {
            #pragma unroll
            for (int mt = 0; mt < 4; ++mt) aAn[mt] = *(const short8*)(wAb + ((kc + 1) * 4 + mt) * 512);
        }
        int k0 = kc * 32 + quad * 8;
        int t = k0 >> 6, ci0 = k0 & 63;
        int cb = (g * 64 + ci0) >> 3;
        int r0 = pos * 8 + 2 * t;
        int key0 = (pos ^ (2 * t)) & 7, key1 = (pos ^ (2 * t + 1)) & 7;
        short8 n0 = *(const short8*)(sh_node + r0 * 256 + ((cb ^ key0) * 8));
        short8 n1 = *(const short8*)(sh_node + (r0 + 1) * 256 + ((cb ^ key1) * 8));
        float a0 = aT[2 * t], a1 = aT[2 * t + 1];
        union { uint4 u; short8 s; } cv;
        #pragma unroll
        for (int e = 0; e < 4; ++e) {
            float lo = fmaf(a0, b2f((u16)n0[2 * e]),     a1 * b2f((u16)n1[2 * e]));
            float hi = fmaf(a0, b2f((u16)n0[2 * e + 1]), a1 * b2f((u16)n1[2 * e + 1]));
            ((u32*)&cv.u)[e] = pk(lo, hi);
        }
        short8 bB = cv.s;
        #pragma unroll
        for (int mt = 0; mt < 4; ++mt)
            accn[mt] = __builtin_amdgcn_mfma_f32_16x16x32_bf16(aAc[mt], bB, accn[mt], 0, 0, 0);
        if (kc < 7) {
            #pragma unroll
            for (int mt = 0; mt < 4; ++mt) aAc[mt] = aAn[mt];
        }
    }
    #pragma unroll
    for (int kc = 0; kc < 2; ++kc) {
        int cb = (g * 64 + kc * 32 + quad * 8) >> 3;
        short8 bS = *(const short8*)(sh_srcq + pos * 256 + ((cb ^ pos) * 8));
        #pragma unroll
        for (int mt = 0; mt < 4; ++mt) {
            short8 aS = *(const short8*)(wS1 + (((g * 2 + kc) * 4 + mt) * 512 + lane * 8));
            accs[mt] = __builtin_amdgcn_mfma_f32_16x16x32_bf16(aS, bS, accs[mt], 0, 0, 0);
        }
    }
    __syncthreads();   // src reads done; reuse sh_srcq as out tile [pos][o]

    u16* outt = sh_srcq;
    #pragma unroll
    for (int mt = 0; mt < 4; ++mt) {
        int ob = g * 64 + mt * 16 + quad * 4;
        float v[4], n1v[4];
        #pragma unroll
        for (int r = 0; r < 4; ++r) {
            int o = ob + r;
            float n1 = fmaxf(accn[mt][r] + bagg1[o], 0.f);
            float s1 = fmaxf(accs[mt][r] + bsrc1[o], 0.f);
            n1v[r] = n1;
            v[r] = n1 + s1;
        }
        if (col < 8) {
            u32* wp = (u32*)&outt[col * 256 + ob];
            wp[0] = pk(v[0], v[1]);
            wp[1] = pk(v[2], v[3]);
        }
        if (bx == 0 && col == 0) {
            #pragma unroll
            for (int r = 0; r < 4; ++r) n1m0[b * 256 + ob + r] = n1v[r];
        }
    }
    __syncthreads();
    {
        int posw = tid >> 5, cc = (tid & 31) * 8;
        if (p0 + posw < MM)
            *(uint4*)&out1[((size_t)b * MMP + p0 + posw) * 256 + cc] = *(const uint4*)&outt[posw * 256 + cc];
    }
}

// ---------- layer2 conv + score2 (blocks x<128, 4 pos each) + score1 (x==128) ----------
__global__ __launch_bounds__(256) void l2conv_k(
    const u16* __restrict__ out1, const float* __restrict__ attnf,
    const float* __restrict__ gt2,
    const u16* __restrict__ wA2, const u16* __restrict__ wS2,
    const float* __restrict__ bagg2, const float* __restrict__ bsrc2,
    const float* __restrict__ gt1m0, const float* __restrict__ n1m0,
    float* __restrict__ outp, float* __restrict__ score2p, float* __restrict__ score1p) {
    __shared__ char shraw[16 * 268 * 4 * 2];
    __shared__ float shred[128];

    int tid = threadIdx.x;
    int b = blockIdx.y;

    if (blockIdx.x == 128) {            // fused score1
        float d = gt1m0[b * 256 + tid] - n1m0[b * 256 + tid];
        float v = d * d;
        #pragma unroll
        for (int off = 32; off > 0; off >>= 1) v += __shfl_down(v, off, 64);
        if ((tid & 63) == 0) shred[tid >> 6] = v;
        __syncthreads();
        if (tid == 0) score1p[b] = 1.f - __expf(-0.5f * (shred[0] + shred[1] + shred[2] + shred[3]));
        return;
    }

    int p0 = blockIdx.x * 4;           // 4 positions per block
    u16* aggl = (u16*)shraw;

    {
        int pos16 = tid >> 4, cc = tid & 15;
        int pos = pos16 & 3;           // slots 0..15 hold pos 0..3 x4 (cols duplicate)
        int m = p0 + pos;
        int c0 = cc * 16;
        int h = c0 >> 6;
        const float* arow = attnf + ((size_t)b * MM2 + m) * 32;
        // bulk-issue all 16 out1 loads + 8 attn loads, then combine+write
        uint4 P0[4], P1[4], Q0[4], Q1[4];
        float a0v[4], a1v[4];
        #pragma unroll
        for (int t = 0; t < 4; ++t) {
            const uint4* r0 = (const uint4*)(out1 + ((size_t)b * MMP + 1 + 8 * m + 2 * t) * 256 + c0);
            const uint4* r1 = (const uint4*)(out1 + ((size_t)b * MMP + 2 + 8 * m + 2 * t) * 256 + c0);
            P0[t] = r0[0]; P1[t] = r0[1];
            Q0[t] = r1[0]; Q1[t] = r1[1];
            a0v[t] = arow[(2 * t) * 4 + h];
            a1v[t] = arow[(2 * t + 1) * 4 + h];
        }
        #pragma unroll
        for (int t = 0; t < 4; ++t) {
            float a0 = a0v[t], a1 = a1v[t];
            u32 w[8];
            {
                u32 pv[4] = {P0[t].x, P0[t].y, P0[t].z, P0[t].w};
                u32 qv[4] = {Q0[t].x, Q0[t].y, Q0[t].z, Q0[t].w};
                #pragma unroll
                for (int e = 0; e < 4; ++e) {
                    float lo = fmaf(bflo(pv[e]), a0, bflo(qv[e]) * a1);
                    float hi = fmaf(bfhi(pv[e]), a0, bfhi(qv[e]) * a1);
                    w[e] = pk(lo, hi);
                }
            }
            {
                u32 pv[4] = {P1[t].x, P1[t].y, P1[t].z, P1[t].w};
                u32 qv[4] = {Q1[t].x, Q1[t].y, Q1[t].z, Q1[t].w};
                #pragma unroll
                for (int e = 0; e < 4; ++e) {
                    float lo = fmaf(bflo(pv[e]), a0, bflo(qv[e]) * a1);
                    float hi = fmaf(bfhi(pv[e]), a0, bfhi(qv[e]) * a1);
                    w[4 + e] = pk(lo, hi);
                }
            }
            u32* dst = (u32*)&aggl[pos16 * 1024 + h * 256 + t * 64 + (c0 & 63)];
            ((uint4*)dst)[0] = make_uint4(w[0], w[1], w[2], w[3]);
            ((uint4*)dst)[1] = make_uint4(w[4], w[5], w[6], w[7]);
        }
    }
    __syncthreads();

    int lane = tid & 63, g = tid >> 6;
    int col = lane & 15, quad = lane >> 4;
    f32x4 accn[4], accs[4];
    #pragma unroll
    for (int mt = 0; mt < 4; ++mt) { accn[mt] = (f32x4){0,0,0,0}; accs[mt] = (f32x4){0,0,0,0}; }

    const u16* wAb = wA2 + (size_t)(g * 8) * 4 * 512 + lane * 8;
    short8 aAc[4];
    #pragma unroll
    for (int mt = 0; mt < 4; ++mt) aAc[mt] = *(const short8*)(wAb + mt * 512);

    #pragma unroll
    for (int kc = 0; kc < 8; ++kc) {
        short8 aAn[4];
        if (kc < 7) {
            #pragma unroll
            for (int mt = 0; mt < 4; ++mt) aAn[mt] = *(const short8*)(wAb + ((kc + 1) * 4 + mt) * 512);
        }
        short8 bB = *(const short8*)&aggl[col * 1024 + g * 256 + kc * 32 + quad * 8];
        #pragma unroll
        for (int mt = 0; mt < 4; ++mt)
            accn[mt] = __builtin_amdgcn_mfma_f32_16x16x32_bf16(aAc[mt], bB, accn[mt], 0, 0, 0);
        if (kc < 7) {
            #pragma unroll
            for (int mt = 0; mt < 4; ++mt) aAc[mt] = aAn[mt];
        }
    }
    {
        int pcol = col & 3;
        #pragma unroll
        for (int kc = 0; kc < 2; ++kc) {
            short8 bS = *(const short8*)(out1 + ((size_t)b * MMP + p0 + pcol) * 256 + g * 64 + kc * 32 + quad * 8);
            #pragma unroll
            for (int mt = 0; mt < 4; ++mt) {
                short8 aS = *(const short8*)(wS2 + (((g * 2 + kc) * 4 + mt) * 512 + lane * 8));
                accs[mt] = __builtin_amdgcn_mfma_f32_16x16x32_bf16(aS, bS, accs[mt], 0, 0, 0);
            }
        }
    }
    __syncthreads();

    float* outt = (float*)shraw;
    float* n2t  = outt + 16 * 268;
    #pragma unroll
    for (int mt = 0; mt < 4; ++mt) {
        #pragma unroll
        for (int r = 0; r < 4; ++r) {
            int o = g * 64 + mt * 16 + quad * 4 + r;
            float n2 = fmaxf(accn[mt][r] + bagg2[o], 0.f);
            float s2 = fmaxf(accs[mt][r] + bsrc2[o], 0.f);
            outt[col * 268 + o] = n2 + s2;
            n2t[col * 268 + o] = n2;
        }
    }
    __syncthreads();

    {
        int pos = tid >> 6, cc = (tid & 63) * 4;
        *(float4*)&outp[((size_t)b * MM2 + p0 + pos) * 256 + cc] = *(const float4*)&outt[pos * 268 + cc];
    }
    if (tid < 64) {
        int pos = tid >> 4, kk = tid & 15;
        const float* grow = gt2 + ((size_t)b * MM2 + p0 + pos) * 256 + kk * 16;
        const float* nrow = n2t + pos * 268 + kk * 16;
        float s = 0.f;
        #pragma unroll
        for (int c = 0; c < 16; ++c) { float d = grow[c] - nrow[c]; s = fmaf(d, d, s); }
        shred[pos * 16 + kk] = s;
    }
    __syncthreads();
    if (tid < 4) {
        float s = 0.f;
        #pragma unroll
        for (int kk = 0; kk < 16; ++kk) s += shred[tid * 16 + kk];
        score2p[(size_t)b * MM2 + p0 + tid] = 1.f - __expf(-0.5f * s);
    }
}

extern "C" void kernel_launch(void* const* d_in, const int* in_sizes, int n_in,
                              void* d_out, int out_size, void* d_ws, size_t ws_size,
                              hipStream_t stream) {
    const float* x     = (const float*)d_in[0];
    const float* gt    = (const float*)d_in[1];
    const float* watt  = (const float*)d_in[2];
    const float* batt  = (const float*)d_in[3];
    const float* wgt1  = (const float*)d_in[4];
    const float* bgt1  = (const float*)d_in[5];
    const float* wgt2  = (const float*)d_in[6];
    const float* bgt2  = (const float*)d_in[7];
    const float* wagg1 = (const float*)d_in[8];
    const float* bagg1 = (const float*)d_in[9];
    const float* wsrc1 = (const float*)d_in[10];
    const float* bsrc1 = (const float*)d_in[11];
    const float* wagg2 = (const float*)d_in[12];
    const float* bagg2 = (const float*)d_in[13];
    const float* wsrc2 = (const float*)d_in[14];
    const float* bsrc2 = (const float*)d_in[15];

    char* ws = (char*)d_ws;
    float* ws_gt2  = (float*)(ws + 0);            // 2 MB
    float* attnf   = (float*)(ws + 2097152);      // 256 KB
    float* n1m0    = (float*)(ws + 2359296);      // 4 KB
    float* gt1m0   = (float*)(ws + 2363392);      // 4 KB
    u16*   wA1     = (u16*)(ws + 2367488);        // 128 KB
    u16*   wS1     = (u16*)(ws + 2498560);        // 32 KB
    u16*   wA2     = (u16*)(ws + 2531328);        // 128 KB
    u16*   wS2     = (u16*)(ws + 2662400);        // 32 KB
    u16*   wattB   = (u16*)(ws + 2695168);        // 8 KB
    u16*   out1    = (u16*)(ws + 2703360);        // 8,421,376 B

    float* outp    = (float*)d_out;               // 2048*256
    float* score1p = outp + 524288;               // 4
    float* score2p = outp + 524292;               // 2048

    setup_k<<<dim3(656), dim3(256), 0, stream>>>(wagg1, wagg2, wsrc1, wsrc2, watt,
                                                 wA1, wA2, wS1, wS2, wattB);
    l1fused_k<<<dim3(577, 4), dim3(256), 0, stream>>>(x, batt, wA1, wS1, wattB, bagg1, bsrc1,
                                                      attnf, out1, n1m0,
                                                      gt, wgt1, bgt1, wgt2, bgt2, ws_gt2, gt1m0);
    l2conv_k<<<dim3(129, 4), dim3(256), 0, stream>>>(out1, attnf, ws_gt2, wA2, wS2, bagg2, bsrc2,
                                                     gt1m0, n1m0, outp, score2p, score1p);
}